// Round 31
// baseline (172.134 us; speedup 1.0000x reference)
//
#include <hip/hip_runtime.h>

#pragma clang fp contract(off)

#define NB 16
#define NV 100000
#define NF 200000
#define NP 65536

// XLA ReduceWindowRewriter, base_length = 16:
// 200000 = 12500*16, then 12500 -> 782 -> 49 -> 4 (sequential windows).
#define B16 16
#define NW0 12500
#define NW1 782
#define NW2 49
#define NW3 4

#define TREE_LVL 12              // search levels served from LDS
#define TREE_N   (1 << TREE_LVL) // 4096 slots (index 0 unused)

// XCD-aware swizzle: batches {2x,2x+1} pin to XCD x (blockIdx%8 round-robin).
__device__ __forceinline__ void xcd_map(int p, int& batch, int& chunk) {
    int r = p & 15;
    batch = 2 * (r & 7) + (r >> 3);
    chunk = p >> 4;
}

// faces are int32 (established bit-identically over rounds 1-30).
__device__ __forceinline__ void load_face(const int* __restrict__ faces,
                                          long long fidx,
                                          int& i0, int& i1, int& i2) {
    const int* p = faces + fidx * 3;
    i0 = p[0]; i1 = p[1]; i2 = p[2];
}

// ---------------------------------------------------------------------------
// FUSED area + window-16 prefix (bit-exact): FMA-contracted area into LDS,
// then re-sum window prefix in identical sequential order. cdf holds RAW
// within-window prefixes; normalization is applied on-the-fly downstream.
// ---------------------------------------------------------------------------
__global__ void area_prefix_kernel(const float* __restrict__ verts,
                                   const int* __restrict__ faces,
                                   float* __restrict__ cdf,
                                   float* __restrict__ s0) {
    __shared__ float S[256];
    int batch, chunk;
    xcd_map(blockIdx.x, batch, chunk);
    int tid = threadIdx.x;
    int i = chunk * 256 + tid;
    bool valid = (i < NF);
    float a = 0.0f;
    if (valid) {
        size_t gid = (size_t)batch * NF + i;
        const float* vb = verts + (size_t)batch * NV * 3;
        int i0, i1, i2;
        load_face(faces, (long long)gid, i0, i1, i2);
        float ax = vb[3 * i0 + 0], ay = vb[3 * i0 + 1], az = vb[3 * i0 + 2];
        float bx = vb[3 * i1 + 0], by = vb[3 * i1 + 1], bz = vb[3 * i1 + 2];
        float cx = vb[3 * i2 + 0], cy = vb[3 * i2 + 1], cz = vb[3 * i2 + 2];
        float v1x = bx - ax, v1y = by - ay, v1z = bz - az;
        float v2x = cx - ax, v2y = cy - ay, v2z = cz - az;
        float nx = fmaf(v1y, v2z, -(v1z * v2y));
        float ny = fmaf(v1z, v2x, -(v1x * v2z));
        float nz = fmaf(v1x, v2y, -(v1y * v2x));
        float ss = fmaf(nz, nz, fmaf(nx, nx, ny * ny));
        float nrm = sqrtf(ss);
        a = nrm / 2.0f;
    }
    S[tid] = a;
    __syncthreads();
    if (valid) {
        int base = tid & ~15;
        float run = S[base];
        for (int p = base + 1; p <= tid; ++p) run = run + S[p];  // seq order
        cdf[(size_t)batch * NF + i] = run;
        if ((tid & 15) == 15)
            s0[(size_t)batch * NW0 + (i >> 4)] = run;
    }
}

// ---------------------------------------------------------------------------
// Stage B + TREE BUILD (merged): per batch, scan s0[12500] (base-16), write
// scanned S0; then build the 4095-node search heap with normalization
// applied on the fly: T[n] = (S0_excl[mid>>4] + cdf_raw[mid]) * rcp — the
// SAME two f32 ops fused_norm used to apply, so values are bit-identical.
// ---------------------------------------------------------------------------
__global__ void midscan_tree_kernel(const float* __restrict__ s0g,
                                    const float* __restrict__ cdf,
                                    float* __restrict__ S0g,
                                    float* __restrict__ Tg,
                                    float* __restrict__ rcps) {
    __shared__ float t0[NW0];
    __shared__ float t1[NW1];
    __shared__ float t2[NW2];
    __shared__ float t3[NW3];
    int b = blockIdx.x;
    for (int i = threadIdx.x; i < NW0; i += blockDim.x)
        t0[i] = s0g[(size_t)b * NW0 + i];
    __syncthreads();
    for (int w = threadIdx.x; w < NW1; w += blockDim.x) {
        int st = w * B16, en = st + B16 < NW0 ? st + B16 : NW0;
        float run = 0.0f;
        for (int p = st; p < en; ++p) { run = run + t0[p]; t0[p] = run; }
        t1[w] = run;
    }
    __syncthreads();
    for (int w = threadIdx.x; w < NW2; w += blockDim.x) {
        int st = w * B16, en = st + B16 < NW1 ? st + B16 : NW1;
        float run = 0.0f;
        for (int p = st; p < en; ++p) { run = run + t1[p]; t1[p] = run; }
        t2[w] = run;
    }
    __syncthreads();
    for (int w = threadIdx.x; w < NW3; w += blockDim.x) {
        int st = w * B16, en = st + B16 < NW2 ? st + B16 : NW2;
        float run = 0.0f;
        for (int p = st; p < en; ++p) { run = run + t2[p]; t2[p] = run; }
        t3[w] = run;
    }
    __syncthreads();
    if (threadIdx.x == 0) {
        float run = 0.0f;
        for (int k = 0; k < NW3; ++k) { run = run + t3[k]; t3[k] = run; }
    }
    __syncthreads();
    for (int i = threadIdx.x; i < NW2; i += blockDim.x) {
        int w = i >> 4;
        float off = (w > 0) ? t3[w - 1] : 0.0f;
        t2[i] = off + t2[i];
    }
    __syncthreads();
    for (int i = threadIdx.x; i < NW1; i += blockDim.x) {
        int w = i >> 4;
        float off = (w > 0) ? t2[w - 1] : 0.0f;
        t1[i] = off + t1[i];
    }
    __syncthreads();
    for (int i = threadIdx.x; i < NW0; i += blockDim.x) {
        int w = i >> 4;
        float off = (w > 0) ? t1[w - 1] : 0.0f;
        t0[i] = off + t0[i];
    }
    __syncthreads();
    for (int i = threadIdx.x; i < NW0; i += blockDim.x)
        S0g[(size_t)b * NW0 + i] = t0[i];

    // ---- tree build (t0 = scanned S0 in LDS) ----
    float total = t0[NW0 - 2] + s0g[(size_t)b * NW0 + NW0 - 1];
    float rcp = 1.0f / total;
    if (threadIdx.x == 0) rcps[b] = rcp;
    const float* c = cdf + (size_t)b * NF;
    float* T = Tg + (size_t)b * TREE_N;
    for (int n = 1 + threadIdx.x; n < TREE_N; n += blockDim.x) {
        int k = 31 - __clz(n);
        int low = 0, high = NF;
        for (int j = k - 1; j >= 0; --j) {
            int mid = (low + high) >> 1;
            if ((n >> j) & 1) low = mid; else high = mid;
        }
        int m = (low + high) >> 1;
        int w = m >> 4;
        float off = (w > 0) ? t0[w - 1] : 0.0f;
        T[n] = (off + c[m]) * rcp;          // identical ops to fused_norm
    }
}

// ---------------------------------------------------------------------------
// Sample: stage per-batch heap into LDS; 12 LDS levels + 6 deep levels with
// on-the-fly normalization ((S0_excl + raw) * rcp — bit-identical values);
// f64 epilogue stored f32.
// ---------------------------------------------------------------------------
__global__ void sample_kernel(const float* __restrict__ verts,
                              const int* __restrict__ faces,
                              const float* __restrict__ e1,
                              const float* __restrict__ e2,
                              const float* __restrict__ u,
                              const float* __restrict__ cdf,
                              const float* __restrict__ S0g,
                              const float* __restrict__ Tg,
                              const float* __restrict__ rcps,
                              float* __restrict__ out) {
    __shared__ float T[TREE_N];
    int batch, chunk;
    xcd_map(blockIdx.x, batch, chunk);
    int b = batch;
    const float* c = cdf + (size_t)b * NF;
    const float* S0b = S0g + (size_t)b * NW0;
    const float* Tb = Tg + (size_t)b * TREE_N;
    float rcp = rcps[b];

    int li = chunk * 256 + threadIdx.x;      // sample index in [0, NP)
    int gid = (b << 16) + li;                // P = 65536
    float uv = u[gid];                       // issue early

    for (int n = threadIdx.x; n < TREE_N; n += blockDim.x)   // coalesced stage
        T[n] = Tb[n];
    __syncthreads();

    int low = 0, high = NF, node = 1;
    #pragma unroll
    for (int it = 0; it < TREE_LVL; ++it) {  // LDS levels
        int mid = (low + high) >> 1;
        bool gl = (uv <= T[node]);
        node = 2 * node + (gl ? 0 : 1);
        if (gl) high = mid; else low = mid;
    }
    #pragma unroll
    for (int it = TREE_LVL; it < 18; ++it) { // deep levels, normalize on load
        int mid = (low + high) >> 1;
        int w = mid >> 4;
        float off = (w > 0) ? S0b[w - 1] : 0.0f;   // L2-hot (800 KB total)
        float val = (off + c[mid]) * rcp;          // identical rounding
        bool gl = (uv <= val);
        if (gl) high = mid; else low = mid;
    }
    int idx = high < NF - 1 ? high : NF - 1;

    const float* vb = verts + (size_t)b * NV * 3;
    int i0, i1, i2;
    load_face(faces, (long long)b * NF + idx, i0, i1, i2);
    double ax = vb[3 * i0 + 0], ay = vb[3 * i0 + 1], az = vb[3 * i0 + 2];
    double bx = vb[3 * i1 + 0], by = vb[3 * i1 + 1], bz = vb[3 * i1 + 2];
    double cx = vb[3 * i2 + 0], cy = vb[3 * i2 + 1], cz = vb[3 * i2 + 2];

    double v1x = bx - ax, v1y = by - ay, v1z = bz - az;
    double v2x = cx - ax, v2y = cy - ay, v2z = cz - az;
    double nx = v1y * v2z - v1z * v2y;
    double ny = v1z * v2x - v1x * v2z;
    double nz = v1x * v2y - v1y * v2x;
    double ss = (nx * nx + ny * ny) + nz * nz;
    double nrm = sqrt(ss);
    double unx = nx / nrm, uny = ny / nrm, unz = nz / nrm;

    double s = sqrt((double)e1[gid]);
    double t = (double)e2[gid];
    double w0 = 1.0 - s;
    double w1 = (1.0 - t) * s;
    double w2 = t * s;
    double px = (ax * w0 + bx * w1) + cx * w2;
    double py = (ay * w0 + by * w1) + cy * w2;
    double pz = (az * w0 + bz * w1) + cz * w2;

    size_t po = (size_t)gid * 3;
    out[po + 0] = (float)px;
    out[po + 1] = (float)py;
    out[po + 2] = (float)pz;
    size_t no = (size_t)NB * NP * 3 + po;
    out[no + 0] = (float)unx;
    out[no + 1] = (float)uny;
    out[no + 2] = (float)unz;
}

extern "C" void kernel_launch(void* const* d_in, const int* in_sizes, int n_in,
                              void* d_out, int out_size, void* d_ws, size_t ws_size,
                              hipStream_t stream) {
    const float* verts = (const float*)d_in[0];  // fp32
    const int*   faces = (const int*)d_in[1];    // int32
    const float* e1    = (const float*)d_in[2];
    const float* e2    = (const float*)d_in[3];
    const float* u     = (const float*)d_in[4];
    float* out = (float*)d_out;

    char* ws = (char*)d_ws;
    float* cdf  = (float*)(ws + 512);                        // 12.8 MB (raw prefixes)
    float* s0   = (float*)(ws + 512 + (size_t)NB * NF * 4);               // 800 KB
    float* S0   = (float*)(ws + 512 + (size_t)NB * NF * 4 + (size_t)NB * NW0 * 4);
    float* Tg   = (float*)(ws + 512 + (size_t)NB * NF * 4 + 2 * (size_t)NB * NW0 * 4);
    float* rcps = (float*)(ws + 512 + (size_t)NB * NF * 4 + 2 * (size_t)NB * NW0 * 4
                               + (size_t)NB * TREE_N * 4);

    // fused area + window-prefix: 16 batches x 782 chunks (XCD-swizzled)
    area_prefix_kernel<<<16 * 782, 256, 0, stream>>>(verts, faces, cdf, s0);

    // scan of window sums + tree build (+rcp), one block per batch
    midscan_tree_kernel<<<NB, 256, 0, stream>>>(s0, cdf, S0, Tg, rcps);

    // sample with staged LDS tree + on-the-fly normalize
    sample_kernel<<<16 * 256, 256, 0, stream>>>(verts, faces, e1, e2, u,
                                                cdf, S0, Tg, rcps, out);
}

// Round 32
// 163.985 us; speedup vs baseline: 1.0497x; 1.0497x over previous
//
#include <hip/hip_runtime.h>

#pragma clang fp contract(off)

#define NB 16
#define NV 100000
#define NF 200000
#define NP 65536

// XLA ReduceWindowRewriter, base_length = 16:
// 200000 = 12500*16, then 12500 -> 782 -> 49 -> 4 (sequential windows).
#define B16 16
#define NW0 12500
#define NW1 782
#define NW2 49
#define NW3 4

#define TREE_LVL 12              // search levels served from LDS
#define TREE_N   (1 << TREE_LVL) // 4096 slots (index 0 unused)

// XCD-aware swizzle: batches {2x,2x+1} pin to XCD x (blockIdx%8 round-robin).
__device__ __forceinline__ void xcd_map(int p, int& batch, int& chunk) {
    int r = p & 15;
    batch = 2 * (r & 7) + (r >> 3);
    chunk = p >> 4;
}

// faces are int32 (established bit-identically over rounds 1-31).
__device__ __forceinline__ void load_face(const int* __restrict__ faces,
                                          long long fidx,
                                          int& i0, int& i1, int& i2) {
    const int* p = faces + fidx * 3;
    i0 = p[0]; i1 = p[1]; i2 = p[2];
}

// ---------------------------------------------------------------------------
// FUSED area + window-16 prefix (bit-exact): FMA-contracted area into LDS,
// then re-sum window prefix in identical sequential order. cdf holds RAW
// within-window prefixes here; fused_norm materializes normalized values.
// ---------------------------------------------------------------------------
__global__ void area_prefix_kernel(const float* __restrict__ verts,
                                   const int* __restrict__ faces,
                                   float* __restrict__ cdf,
                                   float* __restrict__ s0) {
    __shared__ float S[256];
    int batch, chunk;
    xcd_map(blockIdx.x, batch, chunk);
    int tid = threadIdx.x;
    int i = chunk * 256 + tid;
    bool valid = (i < NF);
    float a = 0.0f;
    if (valid) {
        size_t gid = (size_t)batch * NF + i;
        const float* vb = verts + (size_t)batch * NV * 3;
        int i0, i1, i2;
        load_face(faces, (long long)gid, i0, i1, i2);
        float ax = vb[3 * i0 + 0], ay = vb[3 * i0 + 1], az = vb[3 * i0 + 2];
        float bx = vb[3 * i1 + 0], by = vb[3 * i1 + 1], bz = vb[3 * i1 + 2];
        float cx = vb[3 * i2 + 0], cy = vb[3 * i2 + 1], cz = vb[3 * i2 + 2];
        float v1x = bx - ax, v1y = by - ay, v1z = bz - az;
        float v2x = cx - ax, v2y = cy - ay, v2z = cz - az;
        float nx = fmaf(v1y, v2z, -(v1z * v2y));
        float ny = fmaf(v1z, v2x, -(v1x * v2z));
        float nz = fmaf(v1x, v2y, -(v1y * v2x));
        float ss = fmaf(nz, nz, fmaf(nx, nx, ny * ny));
        float nrm = sqrtf(ss);
        a = nrm / 2.0f;
    }
    S[tid] = a;
    __syncthreads();
    if (valid) {
        int base = tid & ~15;
        float run = S[base];
        for (int p = base + 1; p <= tid; ++p) run = run + S[p];  // seq order
        cdf[(size_t)batch * NF + i] = run;
        if ((tid & 15) == 15)
            s0[(size_t)batch * NW0 + (i >> 4)] = run;
    }
}

// ---------------------------------------------------------------------------
// Stage B + TREE BUILD (merged): scan s0[12500] (base-16 structure), write
// scanned S0; then build the 4095-node heap from RAW cdf with the SAME
// (off + raw) * rcp ops fused_norm applies -> bit-identical tree values.
// ---------------------------------------------------------------------------
__global__ void midscan_tree_kernel(const float* __restrict__ s0g,
                                    const float* __restrict__ cdf,
                                    float* __restrict__ S0g,
                                    float* __restrict__ Tg,
                                    float* __restrict__ rcps) {
    __shared__ float t0[NW0];
    __shared__ float t1[NW1];
    __shared__ float t2[NW2];
    __shared__ float t3[NW3];
    int b = blockIdx.x;
    for (int i = threadIdx.x; i < NW0; i += blockDim.x)
        t0[i] = s0g[(size_t)b * NW0 + i];
    __syncthreads();
    for (int w = threadIdx.x; w < NW1; w += blockDim.x) {
        int st = w * B16, en = st + B16 < NW0 ? st + B16 : NW0;
        float run = 0.0f;
        for (int p = st; p < en; ++p) { run = run + t0[p]; t0[p] = run; }
        t1[w] = run;
    }
    __syncthreads();
    for (int w = threadIdx.x; w < NW2; w += blockDim.x) {
        int st = w * B16, en = st + B16 < NW1 ? st + B16 : NW1;
        float run = 0.0f;
        for (int p = st; p < en; ++p) { run = run + t1[p]; t1[p] = run; }
        t2[w] = run;
    }
    __syncthreads();
    for (int w = threadIdx.x; w < NW3; w += blockDim.x) {
        int st = w * B16, en = st + B16 < NW2 ? st + B16 : NW2;
        float run = 0.0f;
        for (int p = st; p < en; ++p) { run = run + t2[p]; t2[p] = run; }
        t3[w] = run;
    }
    __syncthreads();
    if (threadIdx.x == 0) {
        float run = 0.0f;
        for (int k = 0; k < NW3; ++k) { run = run + t3[k]; t3[k] = run; }
    }
    __syncthreads();
    for (int i = threadIdx.x; i < NW2; i += blockDim.x) {
        int w = i >> 4;
        float off = (w > 0) ? t3[w - 1] : 0.0f;
        t2[i] = off + t2[i];
    }
    __syncthreads();
    for (int i = threadIdx.x; i < NW1; i += blockDim.x) {
        int w = i >> 4;
        float off = (w > 0) ? t2[w - 1] : 0.0f;
        t1[i] = off + t1[i];
    }
    __syncthreads();
    for (int i = threadIdx.x; i < NW0; i += blockDim.x) {
        int w = i >> 4;
        float off = (w > 0) ? t1[w - 1] : 0.0f;
        t0[i] = off + t0[i];
    }
    __syncthreads();
    for (int i = threadIdx.x; i < NW0; i += blockDim.x)
        S0g[(size_t)b * NW0 + i] = t0[i];

    // ---- tree build from raw cdf + LDS offsets (bit-identical values) ----
    float total = t0[NW0 - 2] + s0g[(size_t)b * NW0 + NW0 - 1];
    float rcp = 1.0f / total;
    if (threadIdx.x == 0) rcps[b] = rcp;
    const float* c = cdf + (size_t)b * NF;
    float* T = Tg + (size_t)b * TREE_N;
    for (int n = 1 + threadIdx.x; n < TREE_N; n += blockDim.x) {
        int k = 31 - __clz(n);
        int low = 0, high = NF;
        for (int j = k - 1; j >= 0; --j) {
            int mid = (low + high) >> 1;
            if ((n >> j) & 1) low = mid; else high = mid;
        }
        int m = (low + high) >> 1;
        int w = m >> 4;
        float off = (w > 0) ? t0[w - 1] : 0.0f;
        T[n] = (off + c[m]) * rcp;          // identical ops to fused_norm
    }
}

// ---------------------------------------------------------------------------
// FUSED addoff + normalize (bit-exact): materialize normalized cdf for the
// deep search levels: cdf[i] = (off + cdf[i]) * rcp.
// ---------------------------------------------------------------------------
__global__ void fused_norm_kernel(float* __restrict__ cdf,
                                  const float* __restrict__ S0,
                                  const float* __restrict__ rcps) {
    int batch, chunk;
    xcd_map(blockIdx.x, batch, chunk);
    int i = chunk * 256 + threadIdx.x;
    if (i >= NF) return;
    const float* S0b = S0 + (size_t)batch * NW0;
    float rcp = rcps[batch];
    int j = i >> 4;
    float off = (j > 0) ? S0b[j - 1] : 0.0f;
    float* p = cdf + (size_t)batch * NF + i;
    *p = (off + *p) * rcp;
}

// ---------------------------------------------------------------------------
// Sample (R30 structure): stage per-batch heap into LDS; 12 LDS levels +
// 6 global levels on the materialized cdf; f64 epilogue stored f32.
// ---------------------------------------------------------------------------
__global__ void sample_kernel(const float* __restrict__ verts,
                              const int* __restrict__ faces,
                              const float* __restrict__ e1,
                              const float* __restrict__ e2,
                              const float* __restrict__ u,
                              const float* __restrict__ cdf,
                              const float* __restrict__ Tg,
                              float* __restrict__ out) {
    __shared__ float T[TREE_N];
    int batch, chunk;
    xcd_map(blockIdx.x, batch, chunk);
    int b = batch;
    const float* c = cdf + (size_t)b * NF;
    const float* Tb = Tg + (size_t)b * TREE_N;

    int li = chunk * 256 + threadIdx.x;      // sample index in [0, NP)
    int gid = (b << 16) + li;                // P = 65536
    float uv = u[gid];                       // issue before the LDS stage

    for (int n = threadIdx.x; n < TREE_N; n += blockDim.x)   // coalesced stage
        T[n] = Tb[n];
    __syncthreads();

    int low = 0, high = NF, node = 1;
    #pragma unroll
    for (int it = 0; it < TREE_LVL; ++it) {  // LDS levels
        int mid = (low + high) >> 1;
        bool gl = (uv <= T[node]);
        node = 2 * node + (gl ? 0 : 1);
        if (gl) high = mid; else low = mid;
    }
    #pragma unroll
    for (int it = TREE_LVL; it < 18; ++it) { // deep global levels
        int mid = (low + high) >> 1;
        bool gl = (uv <= c[mid]);
        if (gl) high = mid; else low = mid;
    }
    int idx = high < NF - 1 ? high : NF - 1;

    const float* vb = verts + (size_t)b * NV * 3;
    int i0, i1, i2;
    load_face(faces, (long long)b * NF + idx, i0, i1, i2);
    double ax = vb[3 * i0 + 0], ay = vb[3 * i0 + 1], az = vb[3 * i0 + 2];
    double bx = vb[3 * i1 + 0], by = vb[3 * i1 + 1], bz = vb[3 * i1 + 2];
    double cx = vb[3 * i2 + 0], cy = vb[3 * i2 + 1], cz = vb[3 * i2 + 2];

    double v1x = bx - ax, v1y = by - ay, v1z = bz - az;
    double v2x = cx - ax, v2y = cy - ay, v2z = cz - az;
    double nx = v1y * v2z - v1z * v2y;
    double ny = v1z * v2x - v1x * v2z;
    double nz = v1x * v2y - v1y * v2x;
    double ss = (nx * nx + ny * ny) + nz * nz;
    double nrm = sqrt(ss);
    double unx = nx / nrm, uny = ny / nrm, unz = nz / nrm;

    double s = sqrt((double)e1[gid]);
    double t = (double)e2[gid];
    double w0 = 1.0 - s;
    double w1 = (1.0 - t) * s;
    double w2 = t * s;
    double px = (ax * w0 + bx * w1) + cx * w2;
    double py = (ay * w0 + by * w1) + cy * w2;
    double pz = (az * w0 + bz * w1) + cz * w2;

    size_t po = (size_t)gid * 3;
    out[po + 0] = (float)px;
    out[po + 1] = (float)py;
    out[po + 2] = (float)pz;
    size_t no = (size_t)NB * NP * 3 + po;
    out[no + 0] = (float)unx;
    out[no + 1] = (float)uny;
    out[no + 2] = (float)unz;
}

extern "C" void kernel_launch(void* const* d_in, const int* in_sizes, int n_in,
                              void* d_out, int out_size, void* d_ws, size_t ws_size,
                              hipStream_t stream) {
    const float* verts = (const float*)d_in[0];  // fp32
    const int*   faces = (const int*)d_in[1];    // int32
    const float* e1    = (const float*)d_in[2];
    const float* e2    = (const float*)d_in[3];
    const float* u     = (const float*)d_in[4];
    float* out = (float*)d_out;

    char* ws = (char*)d_ws;
    float* cdf  = (float*)(ws + 512);                        // 12.8 MB
    float* s0   = (float*)(ws + 512 + (size_t)NB * NF * 4);               // 800 KB
    float* S0   = (float*)(ws + 512 + (size_t)NB * NF * 4 + (size_t)NB * NW0 * 4);
    float* Tg   = (float*)(ws + 512 + (size_t)NB * NF * 4 + 2 * (size_t)NB * NW0 * 4);
    float* rcps = (float*)(ws + 512 + (size_t)NB * NF * 4 + 2 * (size_t)NB * NW0 * 4
                               + (size_t)NB * TREE_N * 4);

    // fused area + window-prefix: 16 batches x 782 chunks (XCD-swizzled)
    area_prefix_kernel<<<16 * 782, 256, 0, stream>>>(verts, faces, cdf, s0);

    // scan of window sums + tree build (+rcp), one block per batch
    midscan_tree_kernel<<<NB, 256, 0, stream>>>(s0, cdf, S0, Tg, rcps);

    // materialize normalized cdf (deep search levels read this)
    fused_norm_kernel<<<16 * 782, 256, 0, stream>>>(cdf, S0, rcps);

    // sample with staged LDS tree: 16 batches x 256 chunks (XCD-swizzled)
    sample_kernel<<<16 * 256, 256, 0, stream>>>(verts, faces, e1, e2, u, cdf, Tg, out);
}